// Round 17
// baseline (230.162 us; speedup 1.0000x reference)
//
#include <hip/hip_runtime.h>
#include <math.h>

#define NFEAT 128
#define NHID 256
#define NBLK 128  // partition blocks; (block,bucket) segment avg = 8 edges = 32B

typedef __attribute__((ext_vector_type(8))) short short8;
typedef __attribute__((ext_vector_type(4))) float f32x4;

__device__ inline unsigned short f2bf(float f) {
  unsigned u = __float_as_uint(f);
  u += 0x7fffu + ((u >> 16) & 1u);
  return (unsigned short)(u >> 16);
}
__device__ inline float bflo(unsigned u) { return __uint_as_float(u << 16); }
__device__ inline float bfhi(unsigned u) { return __uint_as_float(u & 0xffff0000u); }

// ============ CSR build: deterministic 2-pass partition, no global atomics ==
// bucket = dest >> 6 (64 nodes/bucket); needs N <= 65536 (16-bit packing)

// ---- per-(block,bucket) histogram (blocks 0..NBLK-1) + W-pack (blocks >= NBLK)
__device__ inline void packOne(const float* __restrict__ W,
                               unsigned short* __restrict__ Wp, int idx, int KS,
                               int OUT) {
  int lane = idx & 63;
  int t = idx >> 6;
  int ks = t % KS;
  int nt = t / KS;
  int n = nt * 16 + (lane & 15);
  int k0 = ks * 32 + (lane >> 4) * 8;
  unsigned short v[8];
#pragma unroll
  for (int j = 0; j < 8; j++) v[j] = f2bf(W[(size_t)(k0 + j) * OUT + n]);
  *reinterpret_cast<short8*>(Wp + (size_t)idx * 8) =
      *reinterpret_cast<short8*>(v);
}

__global__ __launch_bounds__(1024) void k_hist_pack(
    const int* __restrict__ col, int* __restrict__ hist2d, int nE, int nb,
    const float* __restrict__ W1, const float* __restrict__ W2,
    unsigned short* __restrict__ W1p, unsigned short* __restrict__ W2p) {
  if (blockIdx.x >= NBLK) {  // pack blocks: 8 x 1024 threads = 8192 items
    int idx = (blockIdx.x - NBLK) * 1024 + threadIdx.x;
    if (idx < 4096) packOne(W1, W1p, idx, 4, 256);
    else packOne(W2, W2p, idx - 4096, 8, 128);
    return;
  }
  __shared__ int h[1024];
  for (int i = threadIdx.x; i < nb; i += 1024) h[i] = 0;
  __syncthreads();
  int chunk = (nE + NBLK - 1) / NBLK;
  int beg = blockIdx.x * chunk, end = min(beg + chunk, nE);
  for (int e = beg + threadIdx.x; e < end; e += 1024)
    atomicAdd(&h[col[e] >> 6], 1);
  __syncthreads();
  for (int i = threadIdx.x; i < nb; i += 1024)
    hist2d[i * NBLK + blockIdx.x] = h[i];
}

// ---- merged scan: block b computes base = sum(a[0..b*256)) directly, then
//      exclusive-scans its own 256 elements. Extra block: head constant. ----
__global__ __launch_bounds__(256) void k_scan(const int* __restrict__ a,
                                              int* __restrict__ out, int S,
                                              const float* __restrict__ b2,
                                              const float* __restrict__ Wl,
                                              const float* __restrict__ bl,
                                              float* __restrict__ Cbuf) {
  int t = threadIdx.x;
  if (blockIdx.x == gridDim.x - 1) {  // C = b2.(Wl_lo+Wl_hi) + bl
    float v = (t < 128) ? b2[t] * (Wl[t] + Wl[128 + t]) : 0.f;
#pragma unroll
    for (int o = 32; o; o >>= 1) v += __shfl_down(v, o);
    __shared__ float fw[4];
    if ((t & 63) == 0) fw[t >> 6] = v;
    __syncthreads();
    if (t == 0) Cbuf[0] = fw[0] + fw[1] + fw[2] + fw[3] + bl[0];
    return;
  }
  __shared__ int sh[256];
  __shared__ int ws[4];
  int b = blockIdx.x;
  int lim = b * 256;  // predecessor range
  int partial = 0;
  for (int i = t; i < lim; i += 256) partial += a[i];
#pragma unroll
  for (int o = 32; o; o >>= 1) partial += __shfl_down(partial, o);
  if ((t & 63) == 0) ws[t >> 6] = partial;
  int i = lim + t;
  int d = (i < S) ? a[i] : 0;
  sh[t] = d;
  __syncthreads();
  int base = ws[0] + ws[1] + ws[2] + ws[3];
  for (int o = 1; o < 256; o <<= 1) {
    int u = (t >= o) ? sh[t - o] : 0;
    __syncthreads();
    sh[t] += u;
    __syncthreads();
  }
  if (i < S) out[i] = base + sh[t] - d;
}

// ---- partition: each block writes its own contiguous segments ----
__global__ __launch_bounds__(1024) void k_part2(const int* __restrict__ row,
                                                const int* __restrict__ col,
                                                const int* __restrict__ sbase,
                                                unsigned* __restrict__ tmp,
                                                int nE, int nb) {
  __shared__ int cur[1024];
  for (int i = threadIdx.x; i < nb; i += 1024)
    cur[i] = sbase[i * NBLK + blockIdx.x];
  __syncthreads();
  int chunk = (nE + NBLK - 1) / NBLK;
  int beg = blockIdx.x * chunk, end = min(beg + chunk, nE);
  for (int e = beg + threadIdx.x; e < end; e += 1024) {
    int c = col[e];
    int pos = atomicAdd(&cur[c >> 6], 1);
    tmp[pos] = ((unsigned)(c & 63) << 16) | (unsigned)row[e];
  }
}

// ---- per-bucket counting sort -> ebuf + offs + dinv; also cvt this bucket's
//      64 feature rows: xs = bf16(dinv[row] * X) ----
__global__ __launch_bounds__(256) void k_bsort_cvt(
    const unsigned* __restrict__ tmp, const int* __restrict__ sbase,
    int* __restrict__ ebuf, int* __restrict__ offs, float* __restrict__ dinv,
    const float* __restrict__ feat, unsigned short* __restrict__ xs, int n,
    int nE, int nb) {
  __shared__ int bins[64], cur[64];
  __shared__ float sdinv[64];
  int b = blockIdx.x;
  int beg = sbase[b * NBLK];
  int end = (b == nb - 1) ? nE : sbase[(b + 1) * NBLK];
  int t = threadIdx.x;
  if (t == 0 && b == nb - 1) offs[n] = nE;
  if (t < 64) bins[t] = 0;
  __syncthreads();
  for (int i = beg + t; i < end; i += 256) atomicAdd(&bins[tmp[i] >> 16], 1);
  __syncthreads();
  if (t < 64) {  // wave 0: exclusive scan of 64 bins via shfl
    int v = bins[t];
    int s = v;
#pragma unroll
    for (int o = 1; o < 64; o <<= 1) {
      int u = __shfl_up(s, o);
      if (t >= o) s += u;
    }
    int off = beg + s - v;
    cur[t] = off;
    float dv = rsqrtf((float)(v + 1));  // +1 self loop
    sdinv[t] = dv;
    int node = b * 64 + t;
    if (node < n) {
      offs[node] = off;
      dinv[node] = dv;
    }
  }
  __syncthreads();
  for (int i = beg + t; i < end; i += 256) {
    unsigned p = tmp[i];
    int pos = atomicAdd(&cur[p >> 16], 1);
    ebuf[pos] = (int)(p & 0xffffu);
  }
  // cvt: 64 rows x 32 float4
  for (int i = t; i < 64 * 32; i += 256) {
    int r = i >> 5;
    int node = b * 64 + r;
    if (node >= n) break;
    float d = sdinv[r];
    float4 v = reinterpret_cast<const float4*>(feat)[(size_t)node * 32 + (i & 31)];
    unsigned short o[4] = {f2bf(v.x * d), f2bf(v.y * d), f2bf(v.z * d),
                           f2bf(v.w * d)};
    reinterpret_cast<ushort4*>(xs)[(size_t)node * 32 + (i & 31)] =
        *reinterpret_cast<ushort4*>(o);
  }
}

// ---------------- bf16 gather-aggregate, 4 edges/VMEM, MLP-2 pipeline -------
// wave = 1 node; lane l: edge slot g=l>>4, feature chunk c=l&15 (uint4 = 8 bf16)
// OUT[i] = bf16( dinv[i]*(G[i] + sum_{src in-edges} G[src]) )
__global__ __launch_bounds__(256) void k_agg_bf(
    const unsigned int* __restrict__ G, const int* __restrict__ offs,
    const int* __restrict__ ebuf, const float* __restrict__ dinv,
    unsigned int* __restrict__ OUTP, int n) {
  int node = blockIdx.x * 4 + (threadIdx.x >> 6);
  if (node >= n) return;
  int lane = threadIdx.x & 63;
  int g = lane >> 4;
  int c = lane & 15;
  int beg = offs[node], end = offs[node + 1];
  float acc[8];
  if (g == 0) {  // self loop handled by group 0
    uint4 s = *reinterpret_cast<const uint4*>(G + (size_t)node * 64 + c * 4);
    acc[0] = bflo(s.x); acc[1] = bfhi(s.x); acc[2] = bflo(s.y); acc[3] = bfhi(s.y);
    acc[4] = bflo(s.z); acc[5] = bfhi(s.z); acc[6] = bflo(s.w); acc[7] = bfhi(s.w);
  } else {
#pragma unroll
    for (int j = 0; j < 8; j++) acc[j] = 0.f;
  }
  int e = beg + g;
  for (; e + 4 < end; e += 8) {  // two independent gathers in flight
    int i0 = ebuf[e], i1 = ebuf[e + 4];
    uint4 v0 = *reinterpret_cast<const uint4*>(G + (size_t)i0 * 64 + c * 4);
    uint4 v1 = *reinterpret_cast<const uint4*>(G + (size_t)i1 * 64 + c * 4);
    acc[0] += bflo(v0.x); acc[1] += bfhi(v0.x);
    acc[2] += bflo(v0.y); acc[3] += bfhi(v0.y);
    acc[4] += bflo(v0.z); acc[5] += bfhi(v0.z);
    acc[6] += bflo(v0.w); acc[7] += bfhi(v0.w);
    acc[0] += bflo(v1.x); acc[1] += bfhi(v1.x);
    acc[2] += bflo(v1.y); acc[3] += bfhi(v1.y);
    acc[4] += bflo(v1.z); acc[5] += bfhi(v1.z);
    acc[6] += bflo(v1.w); acc[7] += bfhi(v1.w);
  }
  if (e < end) {
    uint4 v = *reinterpret_cast<const uint4*>(G + (size_t)ebuf[e] * 64 + c * 4);
    acc[0] += bflo(v.x); acc[1] += bfhi(v.x);
    acc[2] += bflo(v.y); acc[3] += bfhi(v.y);
    acc[4] += bflo(v.z); acc[5] += bfhi(v.z);
    acc[6] += bflo(v.w); acc[7] += bfhi(v.w);
  }
#pragma unroll
  for (int j = 0; j < 8; j++) {  // fold 4 edge-groups into lanes 0..15
    acc[j] += __shfl_down(acc[j], 32);
    acc[j] += __shfl_down(acc[j], 16);
  }
  if (g == 0) {
    float d = dinv[node];
    unsigned o[4];
#pragma unroll
    for (int k = 0; k < 4; k++)
      o[k] = (unsigned)f2bf(acc[2 * k] * d) |
             ((unsigned)f2bf(acc[2 * k + 1] * d) << 16);
    *reinterpret_cast<uint4*>(OUTP + (size_t)node * 64 + c * 4) =
        *reinterpret_cast<uint4*>(o);
  }
}

// ---------------- fused double GEMM + head projection, 32-row tiles ---------
// per block (4 waves): rows r0..r0+31.
//   phase A: h1 = relu(z@W1 + b1)  [32x256] -> LDS (row stride 264 shorts)
//   phase B: g2' = (h1@W2)*dinv    [32x128] -> projected: p = {g2'.Wl_lo, g2'.Wl_hi}
// g2 is NEVER materialized. caller gives 16-row slack in z/dinv/p.
__global__ __launch_bounds__(256) void k_mfma_fused(
    const unsigned short* __restrict__ A, const unsigned short* __restrict__ B1p,
    const unsigned short* __restrict__ B2p, const float* __restrict__ b1,
    const float* __restrict__ dinv, const float* __restrict__ Wl,
    float* __restrict__ P) {
  __shared__ unsigned short sh1[32 * 264];  // +8 pad: 2-way LDS conflicts only
  __shared__ float pacc[32][2];
  int rt0 = blockIdx.x * 2;
  int wave = threadIdx.x >> 6;
  int lane = threadIdx.x & 63;
  int quad = lane >> 4;
  int mrow0 = rt0 * 16 + (lane & 15);
  if (threadIdx.x < 64) pacc[threadIdx.x >> 1][threadIdx.x & 1] = 0.f;

  // ---- phase A: cols wave*64 .. wave*64+63 of h1, two 16-row tiles ----
  f32x4 acc[2][4] = {};
  const short8* Ap0 =
      reinterpret_cast<const short8*>(A + (size_t)mrow0 * NFEAT + quad * 8);
  const short8* Ap1 = reinterpret_cast<const short8*>(
      A + (size_t)(mrow0 + 16) * NFEAT + quad * 8);
#pragma unroll
  for (int ks = 0; ks < 4; ks++) {
    short8 a0 = Ap0[ks * 4];
    short8 a1 = Ap1[ks * 4];
#pragma unroll
    for (int ct = 0; ct < 4; ct++) {
      int nt = wave * 4 + ct;
      short8 b = *reinterpret_cast<const short8*>(
          B1p + ((size_t)(nt * 4 + ks) * 64 + lane) * 8);
      acc[0][ct] = __builtin_amdgcn_mfma_f32_16x16x32_bf16(a0, b, acc[0][ct], 0, 0, 0);
      acc[1][ct] = __builtin_amdgcn_mfma_f32_16x16x32_bf16(a1, b, acc[1][ct], 0, 0, 0);
    }
  }
#pragma unroll
  for (int ct = 0; ct < 4; ct++) {
    int c = (wave * 4 + ct) * 16 + (lane & 15);
    float bv = b1[c];
#pragma unroll
    for (int rg = 0; rg < 2; rg++)
#pragma unroll
      for (int i = 0; i < 4; i++) {
        float v = fmaxf(acc[rg][ct][i] + bv, 0.f);
        sh1[(rg * 16 + quad * 4 + i) * 264 + c] = f2bf(v);
      }
  }
  __syncthreads();

  // ---- phase B: cols wave*32 .. wave*32+31, K=256 from LDS; project to p ----
  f32x4 acc2[2][2] = {};
  const unsigned short* a2_0 = sh1 + (size_t)(lane & 15) * 264 + quad * 8;
  const unsigned short* a2_1 = sh1 + (size_t)(16 + (lane & 15)) * 264 + quad * 8;
#pragma unroll
  for (int ks = 0; ks < 8; ks++) {
    short8 a0 = *reinterpret_cast<const short8*>(a2_0 + ks * 32);
    short8 a1 = *reinterpret_cast<const short8*>(a2_1 + ks * 32);
#pragma unroll
    for (int ct = 0; ct < 2; ct++) {
      int nt = wave * 2 + ct;
      short8 b = *reinterpret_cast<const short8*>(
          B2p + ((size_t)(nt * 8 + ks) * 64 + lane) * 8);
      acc2[0][ct] = __builtin_amdgcn_mfma_f32_16x16x32_bf16(a0, b, acc2[0][ct], 0, 0, 0);
      acc2[1][ct] = __builtin_amdgcn_mfma_f32_16x16x32_bf16(a1, b, acc2[1][ct], 0, 0, 0);
    }
  }
  float p1[2][4] = {}, p2[2][4] = {};
#pragma unroll
  for (int rg = 0; rg < 2; rg++) {
    int r0 = (rt0 + rg) * 16 + quad * 4;
    float dv[4];
#pragma unroll
    for (int i = 0; i < 4; i++) dv[i] = dinv[r0 + i];
#pragma unroll
    for (int ct = 0; ct < 2; ct++) {
      int c = (wave * 2 + ct) * 16 + (lane & 15);
      float wl1 = Wl[c], wl2 = Wl[128 + c];
#pragma unroll
      for (int i = 0; i < 4; i++) {
        float v = acc2[rg][ct][i] * dv[i];
        p1[rg][i] = fmaf(v, wl1, p1[rg][i]);
        p2[rg][i] = fmaf(v, wl2, p2[rg][i]);
      }
    }
  }
  // reduce over the 16 lanes of this quad (cols), then cross-wave via LDS
#pragma unroll
  for (int rg = 0; rg < 2; rg++)
#pragma unroll
    for (int i = 0; i < 4; i++) {
#pragma unroll
      for (int o = 8; o; o >>= 1) {
        p1[rg][i] += __shfl_xor(p1[rg][i], o);
        p2[rg][i] += __shfl_xor(p2[rg][i], o);
      }
    }
  if ((lane & 15) == 0) {
#pragma unroll
    for (int rg = 0; rg < 2; rg++)
#pragma unroll
      for (int i = 0; i < 4; i++) {
        int row = rg * 16 + quad * 4 + i;
        atomicAdd(&pacc[row][0], p1[rg][i]);
        atomicAdd(&pacc[row][1], p2[rg][i]);
      }
  }
  __syncthreads();
  if (threadIdx.x < 64) {
    int row = threadIdx.x >> 1, comp = threadIdx.x & 1;
    P[(size_t)(rt0 * 16 + row) * 2 + comp] = pacc[row][comp];
  }
}

// ---------------- scalar aggregation of projections ----------------
// q[i] = dinv[i] * (p[i] + sum_{src in-edges} p[src])   (head consts folded in C)
__global__ __launch_bounds__(256) void k_agg_s(const float2* __restrict__ p,
                                               const int* __restrict__ offs,
                                               const int* __restrict__ ebuf,
                                               const float* __restrict__ dinv,
                                               float2* __restrict__ q, int n) {
  int i = blockIdx.x * 256 + threadIdx.x;
  if (i >= n) return;
  int beg = offs[i], end = offs[i + 1];
  float2 s = p[i];
  int e = beg;
  for (; e + 4 <= end; e += 4) {
    int s0 = ebuf[e], s1 = ebuf[e + 1], s2 = ebuf[e + 2], s3 = ebuf[e + 3];
    float2 v0 = p[s0], v1 = p[s1], v2 = p[s2], v3 = p[s3];
    s.x += v0.x + v1.x + v2.x + v3.x;
    s.y += v0.y + v1.y + v2.y + v3.y;
  }
  for (; e < end; e++) {
    float2 v = p[ebuf[e]];
    s.x += v.x;
    s.y += v.y;
  }
  float d = dinv[i];
  q[i] = make_float2(s.x * d, s.y * d);
}

// ---------------- link head: sigmoid(q1[m0] + q2[m1] + C) ----------------
__global__ __launch_bounds__(256) void k_head2(const float2* __restrict__ q,
                                               const int* __restrict__ mask,
                                               const float* __restrict__ Cbuf,
                                               float* __restrict__ out, int P) {
  int p = blockIdx.x * 256 + threadIdx.x;
  if (p >= P) return;
  int m0 = mask[2 * p], m1 = mask[2 * p + 1];
  float s = q[m0].x + q[m1].y + Cbuf[0];
  out[p] = 1.0f / (1.0f + expf(-s));
}

extern "C" void kernel_launch(void* const* d_in, const int* in_sizes, int n_in,
                              void* d_out, int out_size, void* d_ws,
                              size_t ws_size, hipStream_t stream) {
  const int* edge = (const int*)d_in[0];
  const float* feat = (const float*)d_in[1];
  const int* mask = (const int*)d_in[2];
  const float* W1 = (const float*)d_in[3];
  const float* b1 = (const float*)d_in[4];
  const float* W2 = (const float*)d_in[5];
  const float* b2 = (const float*)d_in[6];
  const float* Wl = (const float*)d_in[7];
  const float* bl = (const float*)d_in[8];
  float* out = (float*)d_out;

  const int E = in_sizes[0] / 2;
  const int N = in_sizes[1] / NFEAT;  // must be <= 65536 (16-bit packing)
  const int P = in_sizes[2] / 2;
  const int* rowp = edge;
  const int* colp = edge + E;
  const int nrt = N / 16;             // 3125 for N=50000
  const int nb = (N + 63) / 64;       // 782 buckets (<= 1024 required)
  const int S = nb * NBLK;            // 100096 hist entries
  const int nS = (S + 255) / 256;     // 392 scan chunks

  auto aln = [](size_t x) { return (x + 255) & ~(size_t)255; };
  const size_t rowSlack = (size_t)16 * NFEAT * 2;  // 16-row tail slack
  char* w = (char*)d_ws;
  int* hist2d = (int*)w;           w += aln((size_t)S * 4);
  int* sbase = (int*)w;            w += aln((size_t)S * 4);
  float* Cbuf = (float*)w;         w += aln(256);
  int* offs = (int*)w;             w += aln((size_t)(N + 1) * 4);
  int* ebuf = (int*)w;             w += aln((size_t)E * 4);
  unsigned* tmp = (unsigned*)w;    w += aln((size_t)E * 4);
  float* dinv = (float*)w;         w += aln((size_t)N * 4 + 1024);
  unsigned short* xs = (unsigned short*)w;  w += aln((size_t)N * NFEAT * 2);
  unsigned short* z = (unsigned short*)w;   w += aln((size_t)N * NFEAT * 2 + rowSlack);
  float* p = (float*)w;            w += aln((size_t)(N + 32) * 8);
  float2* q = (float2*)w;          w += aln((size_t)N * 8);
  unsigned short* W1p = (unsigned short*)w; w += aln((size_t)NFEAT * NHID * 2);
  unsigned short* W2p = (unsigned short*)w; w += aln((size_t)NHID * NFEAT * 2);

  // ---- CSR build: deterministic 2-pass partition (+ W pack on spare blocks)
  k_hist_pack<<<NBLK + 8, 1024, 0, stream>>>(colp, hist2d, E, nb, W1, W2, W1p,
                                             W2p);
  // merged scan (chunk-base computed in-kernel) + head const on extra block
  k_scan<<<nS + 1, 256, 0, stream>>>(hist2d, sbase, S, b2, Wl, bl, Cbuf);
  k_part2<<<NBLK, 1024, 0, stream>>>(rowp, colp, sbase, tmp, E, nb);
  // bsort + per-bucket cvt: ebuf/offs/dinv + xs = bf16(dinv * X)
  k_bsort_cvt<<<nb, 256, 0, stream>>>(tmp, sbase, ebuf, offs, dinv, feat, xs,
                                      N, E, nb);
  // z = dinv .* (sum_in xs + xs_self)            [= A_norm @ X, bf16]
  k_agg_bf<<<(N + 3) / 4, 256, 0, stream>>>((const unsigned*)xs, offs, ebuf,
                                            dinv, (unsigned*)z, N);
  // p[i] = {(dinv_i*(relu(z@W1+b1)@W2)_i) . Wl_lo, . Wl_hi}  (g2 not stored)
  k_mfma_fused<<<(nrt + 1) / 2, 256, 0, stream>>>(z, W1p, W2p, b1, dinv, Wl, p);
  // q[i] = dinv[i]*(p[i] + sum_in p[src])
  k_agg_s<<<(N + 255) / 256, 256, 0, stream>>>((const float2*)p, offs, ebuf,
                                               dinv, q, N);
  // head: out = sigmoid(q1[m0] + q2[m1] + C)
  k_head2<<<(P + 255) / 256, 256, 0, stream>>>(q, mask, Cbuf, out, P);
}

// Round 18
// 172.745 us; speedup vs baseline: 1.3324x; 1.3324x over previous
//
#include <hip/hip_runtime.h>
#include <math.h>

#define NFEAT 128
#define NHID 256
#define NBLK 128  // partition blocks; (block,bucket) segment avg = 8 edges = 32B

typedef __attribute__((ext_vector_type(8))) short short8;
typedef __attribute__((ext_vector_type(4))) float f32x4;

__device__ inline unsigned short f2bf(float f) {
  unsigned u = __float_as_uint(f);
  u += 0x7fffu + ((u >> 16) & 1u);
  return (unsigned short)(u >> 16);
}
__device__ inline float bflo(unsigned u) { return __uint_as_float(u << 16); }
__device__ inline float bfhi(unsigned u) { return __uint_as_float(u & 0xffff0000u); }

// ============ CSR build: deterministic 2-pass partition, no global atomics ==
// bucket = dest >> 6 (64 nodes/bucket); needs N <= 65536 (16-bit packing)

// ---- per-(block,bucket) histogram (blocks 0..NBLK-1) + W-pack (blocks >= NBLK)
__device__ inline void packOne(const float* __restrict__ W,
                               unsigned short* __restrict__ Wp, int idx, int KS,
                               int OUT) {
  int lane = idx & 63;
  int t = idx >> 6;
  int ks = t % KS;
  int nt = t / KS;
  int n = nt * 16 + (lane & 15);
  int k0 = ks * 32 + (lane >> 4) * 8;
  unsigned short v[8];
#pragma unroll
  for (int j = 0; j < 8; j++) v[j] = f2bf(W[(size_t)(k0 + j) * OUT + n]);
  *reinterpret_cast<short8*>(Wp + (size_t)idx * 8) =
      *reinterpret_cast<short8*>(v);
}

__global__ __launch_bounds__(1024) void k_hist_pack(
    const int* __restrict__ col, int* __restrict__ hist2d, int nE, int nb,
    const float* __restrict__ W1, const float* __restrict__ W2,
    unsigned short* __restrict__ W1p, unsigned short* __restrict__ W2p) {
  if (blockIdx.x >= NBLK) {  // pack blocks: 8 x 1024 threads = 8192 items
    int idx = (blockIdx.x - NBLK) * 1024 + threadIdx.x;
    if (idx < 4096) packOne(W1, W1p, idx, 4, 256);
    else packOne(W2, W2p, idx - 4096, 8, 128);
    return;
  }
  __shared__ int h[1024];
  for (int i = threadIdx.x; i < nb; i += 1024) h[i] = 0;
  __syncthreads();
  int chunk = (nE + NBLK - 1) / NBLK;
  int beg = blockIdx.x * chunk, end = min(beg + chunk, nE);
  for (int e = beg + threadIdx.x; e < end; e += 1024)
    atomicAdd(&h[col[e] >> 6], 1);
  __syncthreads();
  for (int i = threadIdx.x; i < nb; i += 1024)
    hist2d[i * NBLK + blockIdx.x] = h[i];
}

// ---- scan phase 1: per-256-chunk sums; last block computes head constant ----
__global__ __launch_bounds__(256) void k_bsum(const int* __restrict__ a,
                                              int* __restrict__ psum, int S,
                                              const float* __restrict__ b2,
                                              const float* __restrict__ Wl,
                                              const float* __restrict__ bl,
                                              float* __restrict__ Cbuf) {
  int t = threadIdx.x;
  if (blockIdx.x == gridDim.x - 1) {  // C = b2.(Wl_lo+Wl_hi) + bl
    float v = (t < 128) ? b2[t] * (Wl[t] + Wl[128 + t]) : 0.f;
#pragma unroll
    for (int o = 32; o; o >>= 1) v += __shfl_down(v, o);
    __shared__ float fw[4];
    if ((t & 63) == 0) fw[t >> 6] = v;
    __syncthreads();
    if (t == 0) Cbuf[0] = fw[0] + fw[1] + fw[2] + fw[3] + bl[0];
    return;
  }
  int i = blockIdx.x * 256 + t;
  int v = (i < S) ? a[i] : 0;
#pragma unroll
  for (int o = 32; o; o >>= 1) v += __shfl_down(v, o);
  __shared__ int ws[4];
  if ((t & 63) == 0) ws[t >> 6] = v;
  __syncthreads();
  if (t == 0) psum[blockIdx.x] = ws[0] + ws[1] + ws[2] + ws[3];
}

// ---- scan phase 2+3 merged: each block redundantly reduces psum[0..b) for
//      its base, then scans its own 256 elements ----
__global__ __launch_bounds__(256) void k_s3m(const int* __restrict__ a,
                                             const int* __restrict__ psum,
                                             int* __restrict__ out, int S) {
  __shared__ int sh[256];
  __shared__ int ws[4];
  int t = threadIdx.x;
  int b = blockIdx.x;
  int partial = 0;
  for (int i = t; i < b; i += 256) partial += psum[i];
#pragma unroll
  for (int o = 32; o; o >>= 1) partial += __shfl_down(partial, o);
  if ((t & 63) == 0) ws[t >> 6] = partial;
  int i = b * 256 + t;
  int d = (i < S) ? a[i] : 0;
  sh[t] = d;
  __syncthreads();
  int base = ws[0] + ws[1] + ws[2] + ws[3];
  for (int o = 1; o < 256; o <<= 1) {
    int u = (t >= o) ? sh[t - o] : 0;
    __syncthreads();
    sh[t] += u;
    __syncthreads();
  }
  if (i < S) out[i] = base + sh[t] - d;
}

// ---- partition: each block writes its own contiguous segments ----
__global__ __launch_bounds__(1024) void k_part2(const int* __restrict__ row,
                                                const int* __restrict__ col,
                                                const int* __restrict__ sbase,
                                                unsigned* __restrict__ tmp,
                                                int nE, int nb) {
  __shared__ int cur[1024];
  for (int i = threadIdx.x; i < nb; i += 1024)
    cur[i] = sbase[i * NBLK + blockIdx.x];
  __syncthreads();
  int chunk = (nE + NBLK - 1) / NBLK;
  int beg = blockIdx.x * chunk, end = min(beg + chunk, nE);
  for (int e = beg + threadIdx.x; e < end; e += 1024) {
    int c = col[e];
    int pos = atomicAdd(&cur[c >> 6], 1);
    tmp[pos] = ((unsigned)(c & 63) << 16) | (unsigned)row[e];
  }
}

// ---- per-bucket counting sort -> ebuf + offs + dinv; also cvt this bucket's
//      64 feature rows: xs = bf16(dinv[row] * X) ----
__global__ __launch_bounds__(256) void k_bsort_cvt(
    const unsigned* __restrict__ tmp, const int* __restrict__ sbase,
    int* __restrict__ ebuf, int* __restrict__ offs, float* __restrict__ dinv,
    const float* __restrict__ feat, unsigned short* __restrict__ xs, int n,
    int nE, int nb) {
  __shared__ int bins[64], cur[64];
  __shared__ float sdinv[64];
  int b = blockIdx.x;
  int beg = sbase[b * NBLK];
  int end = (b == nb - 1) ? nE : sbase[(b + 1) * NBLK];
  int t = threadIdx.x;
  if (t == 0 && b == nb - 1) offs[n] = nE;
  if (t < 64) bins[t] = 0;
  __syncthreads();
  for (int i = beg + t; i < end; i += 256) atomicAdd(&bins[tmp[i] >> 16], 1);
  __syncthreads();
  if (t < 64) {  // wave 0: exclusive scan of 64 bins via shfl
    int v = bins[t];
    int s = v;
#pragma unroll
    for (int o = 1; o < 64; o <<= 1) {
      int u = __shfl_up(s, o);
      if (t >= o) s += u;
    }
    int off = beg + s - v;
    cur[t] = off;
    float dv = rsqrtf((float)(v + 1));  // +1 self loop
    sdinv[t] = dv;
    int node = b * 64 + t;
    if (node < n) {
      offs[node] = off;
      dinv[node] = dv;
    }
  }
  __syncthreads();
  for (int i = beg + t; i < end; i += 256) {
    unsigned p = tmp[i];
    int pos = atomicAdd(&cur[p >> 16], 1);
    ebuf[pos] = (int)(p & 0xffffu);
  }
  // cvt: 64 rows x 32 float4
  for (int i = t; i < 64 * 32; i += 256) {
    int r = i >> 5;
    int node = b * 64 + r;
    if (node >= n) break;
    float d = sdinv[r];
    float4 v = reinterpret_cast<const float4*>(feat)[(size_t)node * 32 + (i & 31)];
    unsigned short o[4] = {f2bf(v.x * d), f2bf(v.y * d), f2bf(v.z * d),
                           f2bf(v.w * d)};
    reinterpret_cast<ushort4*>(xs)[(size_t)node * 32 + (i & 31)] =
        *reinterpret_cast<ushort4*>(o);
  }
}

// ---------------- bf16 gather-aggregate, 4 edges/VMEM, MLP-2 pipeline -------
// wave = 1 node; lane l: edge slot g=l>>4, feature chunk c=l&15 (uint4 = 8 bf16)
// OUT[i] = bf16( dinv[i]*(G[i] + sum_{src in-edges} G[src]) )
__global__ __launch_bounds__(256) void k_agg_bf(
    const unsigned int* __restrict__ G, const int* __restrict__ offs,
    const int* __restrict__ ebuf, const float* __restrict__ dinv,
    unsigned int* __restrict__ OUTP, int n) {
  int node = blockIdx.x * 4 + (threadIdx.x >> 6);
  if (node >= n) return;
  int lane = threadIdx.x & 63;
  int g = lane >> 4;
  int c = lane & 15;
  int beg = offs[node], end = offs[node + 1];
  float acc[8];
  if (g == 0) {  // self loop handled by group 0
    uint4 s = *reinterpret_cast<const uint4*>(G + (size_t)node * 64 + c * 4);
    acc[0] = bflo(s.x); acc[1] = bfhi(s.x); acc[2] = bflo(s.y); acc[3] = bfhi(s.y);
    acc[4] = bflo(s.z); acc[5] = bfhi(s.z); acc[6] = bflo(s.w); acc[7] = bfhi(s.w);
  } else {
#pragma unroll
    for (int j = 0; j < 8; j++) acc[j] = 0.f;
  }
  int e = beg + g;
  for (; e + 4 < end; e += 8) {  // two independent gathers in flight
    int i0 = ebuf[e], i1 = ebuf[e + 4];
    uint4 v0 = *reinterpret_cast<const uint4*>(G + (size_t)i0 * 64 + c * 4);
    uint4 v1 = *reinterpret_cast<const uint4*>(G + (size_t)i1 * 64 + c * 4);
    acc[0] += bflo(v0.x); acc[1] += bfhi(v0.x);
    acc[2] += bflo(v0.y); acc[3] += bfhi(v0.y);
    acc[4] += bflo(v0.z); acc[5] += bfhi(v0.z);
    acc[6] += bflo(v0.w); acc[7] += bfhi(v0.w);
    acc[0] += bflo(v1.x); acc[1] += bfhi(v1.x);
    acc[2] += bflo(v1.y); acc[3] += bfhi(v1.y);
    acc[4] += bflo(v1.z); acc[5] += bfhi(v1.z);
    acc[6] += bflo(v1.w); acc[7] += bfhi(v1.w);
  }
  if (e < end) {
    uint4 v = *reinterpret_cast<const uint4*>(G + (size_t)ebuf[e] * 64 + c * 4);
    acc[0] += bflo(v.x); acc[1] += bfhi(v.x);
    acc[2] += bflo(v.y); acc[3] += bfhi(v.y);
    acc[4] += bflo(v.z); acc[5] += bfhi(v.z);
    acc[6] += bflo(v.w); acc[7] += bfhi(v.w);
  }
#pragma unroll
  for (int j = 0; j < 8; j++) {  // fold 4 edge-groups into lanes 0..15
    acc[j] += __shfl_down(acc[j], 32);
    acc[j] += __shfl_down(acc[j], 16);
  }
  if (g == 0) {
    float d = dinv[node];
    unsigned o[4];
#pragma unroll
    for (int k = 0; k < 4; k++)
      o[k] = (unsigned)f2bf(acc[2 * k] * d) |
             ((unsigned)f2bf(acc[2 * k + 1] * d) << 16);
    *reinterpret_cast<uint4*>(OUTP + (size_t)node * 64 + c * 4) =
        *reinterpret_cast<uint4*>(o);
  }
}

// ---------------- fused double GEMM + head projection, 32-row tiles ---------
// per block (4 waves): rows r0..r0+31.
//   phase A: h1 = relu(z@W1 + b1)  [32x256] -> LDS (row stride 264 shorts)
//   phase B: g2' = (h1@W2)*dinv    [32x128] -> projected: p = {g2'.Wl_lo, g2'.Wl_hi}
// g2 is NEVER materialized. caller gives 16-row slack in z/dinv/p.
__global__ __launch_bounds__(256) void k_mfma_fused(
    const unsigned short* __restrict__ A, const unsigned short* __restrict__ B1p,
    const unsigned short* __restrict__ B2p, const float* __restrict__ b1,
    const float* __restrict__ dinv, const float* __restrict__ Wl,
    float* __restrict__ P) {
  __shared__ unsigned short sh1[32 * 264];  // +8 pad: 2-way LDS conflicts only
  __shared__ float pacc[32][2];
  int rt0 = blockIdx.x * 2;
  int wave = threadIdx.x >> 6;
  int lane = threadIdx.x & 63;
  int quad = lane >> 4;
  int mrow0 = rt0 * 16 + (lane & 15);
  if (threadIdx.x < 64) pacc[threadIdx.x >> 1][threadIdx.x & 1] = 0.f;

  // ---- phase A: cols wave*64 .. wave*64+63 of h1, two 16-row tiles ----
  f32x4 acc[2][4] = {};
  const short8* Ap0 =
      reinterpret_cast<const short8*>(A + (size_t)mrow0 * NFEAT + quad * 8);
  const short8* Ap1 = reinterpret_cast<const short8*>(
      A + (size_t)(mrow0 + 16) * NFEAT + quad * 8);
#pragma unroll
  for (int ks = 0; ks < 4; ks++) {
    short8 a0 = Ap0[ks * 4];
    short8 a1 = Ap1[ks * 4];
#pragma unroll
    for (int ct = 0; ct < 4; ct++) {
      int nt = wave * 4 + ct;
      short8 b = *reinterpret_cast<const short8*>(
          B1p + ((size_t)(nt * 4 + ks) * 64 + lane) * 8);
      acc[0][ct] = __builtin_amdgcn_mfma_f32_16x16x32_bf16(a0, b, acc[0][ct], 0, 0, 0);
      acc[1][ct] = __builtin_amdgcn_mfma_f32_16x16x32_bf16(a1, b, acc[1][ct], 0, 0, 0);
    }
  }
#pragma unroll
  for (int ct = 0; ct < 4; ct++) {
    int c = (wave * 4 + ct) * 16 + (lane & 15);
    float bv = b1[c];
#pragma unroll
    for (int rg = 0; rg < 2; rg++)
#pragma unroll
      for (int i = 0; i < 4; i++) {
        float v = fmaxf(acc[rg][ct][i] + bv, 0.f);
        sh1[(rg * 16 + quad * 4 + i) * 264 + c] = f2bf(v);
      }
  }
  __syncthreads();

  // ---- phase B: cols wave*32 .. wave*32+31, K=256 from LDS; project to p ----
  f32x4 acc2[2][2] = {};
  const unsigned short* a2_0 = sh1 + (size_t)(lane & 15) * 264 + quad * 8;
  const unsigned short* a2_1 = sh1 + (size_t)(16 + (lane & 15)) * 264 + quad * 8;
#pragma unroll
  for (int ks = 0; ks < 8; ks++) {
    short8 a0 = *reinterpret_cast<const short8*>(a2_0 + ks * 32);
    short8 a1 = *reinterpret_cast<const short8*>(a2_1 + ks * 32);
#pragma unroll
    for (int ct = 0; ct < 2; ct++) {
      int nt = wave * 2 + ct;
      short8 b = *reinterpret_cast<const short8*>(
          B2p + ((size_t)(nt * 8 + ks) * 64 + lane) * 8);
      acc2[0][ct] = __builtin_amdgcn_mfma_f32_16x16x32_bf16(a0, b, acc2[0][ct], 0, 0, 0);
      acc2[1][ct] = __builtin_amdgcn_mfma_f32_16x16x32_bf16(a1, b, acc2[1][ct], 0, 0, 0);
    }
  }
  float p1[2][4] = {}, p2[2][4] = {};
#pragma unroll
  for (int rg = 0; rg < 2; rg++) {
    int r0 = (rt0 + rg) * 16 + quad * 4;
    float dv[4];
#pragma unroll
    for (int i = 0; i < 4; i++) dv[i] = dinv[r0 + i];
#pragma unroll
    for (int ct = 0; ct < 2; ct++) {
      int c = (wave * 2 + ct) * 16 + (lane & 15);
      float wl1 = Wl[c], wl2 = Wl[128 + c];
#pragma unroll
      for (int i = 0; i < 4; i++) {
        float v = acc2[rg][ct][i] * dv[i];
        p1[rg][i] = fmaf(v, wl1, p1[rg][i]);
        p2[rg][i] = fmaf(v, wl2, p2[rg][i]);
      }
    }
  }
  // reduce over the 16 lanes of this quad (cols), then cross-wave via LDS
#pragma unroll
  for (int rg = 0; rg < 2; rg++)
#pragma unroll
    for (int i = 0; i < 4; i++) {
#pragma unroll
      for (int o = 8; o; o >>= 1) {
        p1[rg][i] += __shfl_xor(p1[rg][i], o);
        p2[rg][i] += __shfl_xor(p2[rg][i], o);
      }
    }
  if ((lane & 15) == 0) {
#pragma unroll
    for (int rg = 0; rg < 2; rg++)
#pragma unroll
      for (int i = 0; i < 4; i++) {
        int row = rg * 16 + quad * 4 + i;
        atomicAdd(&pacc[row][0], p1[rg][i]);
        atomicAdd(&pacc[row][1], p2[rg][i]);
      }
  }
  __syncthreads();
  if (threadIdx.x < 64) {
    int row = threadIdx.x >> 1, comp = threadIdx.x & 1;
    P[(size_t)(rt0 * 16 + row) * 2 + comp] = pacc[row][comp];
  }
}

// ---------------- scalar aggregation of projections ----------------
// q[i] = dinv[i] * (p[i] + sum_{src in-edges} p[src])   (head consts folded in C)
__global__ __launch_bounds__(256) void k_agg_s(const float2* __restrict__ p,
                                               const int* __restrict__ offs,
                                               const int* __restrict__ ebuf,
                                               const float* __restrict__ dinv,
                                               float2* __restrict__ q, int n) {
  int i = blockIdx.x * 256 + threadIdx.x;
  if (i >= n) return;
  int beg = offs[i], end = offs[i + 1];
  float2 s = p[i];
  int e = beg;
  for (; e + 4 <= end; e += 4) {
    int s0 = ebuf[e], s1 = ebuf[e + 1], s2 = ebuf[e + 2], s3 = ebuf[e + 3];
    float2 v0 = p[s0], v1 = p[s1], v2 = p[s2], v3 = p[s3];
    s.x += v0.x + v1.x + v2.x + v3.x;
    s.y += v0.y + v1.y + v2.y + v3.y;
  }
  for (; e < end; e++) {
    float2 v = p[ebuf[e]];
    s.x += v.x;
    s.y += v.y;
  }
  float d = dinv[i];
  q[i] = make_float2(s.x * d, s.y * d);
}

// ---------------- link head: sigmoid(q1[m0] + q2[m1] + C) ----------------
__global__ __launch_bounds__(256) void k_head2(const float2* __restrict__ q,
                                               const int* __restrict__ mask,
                                               const float* __restrict__ Cbuf,
                                               float* __restrict__ out, int P) {
  int p = blockIdx.x * 256 + threadIdx.x;
  if (p >= P) return;
  int m0 = mask[2 * p], m1 = mask[2 * p + 1];
  float s = q[m0].x + q[m1].y + Cbuf[0];
  out[p] = 1.0f / (1.0f + expf(-s));
}

extern "C" void kernel_launch(void* const* d_in, const int* in_sizes, int n_in,
                              void* d_out, int out_size, void* d_ws,
                              size_t ws_size, hipStream_t stream) {
  const int* edge = (const int*)d_in[0];
  const float* feat = (const float*)d_in[1];
  const int* mask = (const int*)d_in[2];
  const float* W1 = (const float*)d_in[3];
  const float* b1 = (const float*)d_in[4];
  const float* W2 = (const float*)d_in[5];
  const float* b2 = (const float*)d_in[6];
  const float* Wl = (const float*)d_in[7];
  const float* bl = (const float*)d_in[8];
  float* out = (float*)d_out;

  const int E = in_sizes[0] / 2;
  const int N = in_sizes[1] / NFEAT;  // must be <= 65536 (16-bit packing)
  const int P = in_sizes[2] / 2;
  const int* rowp = edge;
  const int* colp = edge + E;
  const int nrt = N / 16;             // 3125 for N=50000
  const int nb = (N + 63) / 64;       // 782 buckets (<= 1024 required)
  const int S = nb * NBLK;            // 100096 hist entries
  const int nS = (S + 255) / 256;     // 392 scan chunks (<= 1024 required)

  auto aln = [](size_t x) { return (x + 255) & ~(size_t)255; };
  const size_t rowSlack = (size_t)16 * NFEAT * 2;  // 16-row tail slack
  char* w = (char*)d_ws;
  int* hist2d = (int*)w;           w += aln((size_t)S * 4);
  int* sbase = (int*)w;            w += aln((size_t)S * 4);
  int* psum = (int*)w;             w += aln((size_t)1024 * 4);
  float* Cbuf = (float*)w;         w += aln(256);
  int* offs = (int*)w;             w += aln((size_t)(N + 1) * 4);
  int* ebuf = (int*)w;             w += aln((size_t)E * 4);
  unsigned* tmp = (unsigned*)w;    w += aln((size_t)E * 4);
  float* dinv = (float*)w;         w += aln((size_t)N * 4 + 1024);
  unsigned short* xs = (unsigned short*)w;  w += aln((size_t)N * NFEAT * 2);
  unsigned short* z = (unsigned short*)w;   w += aln((size_t)N * NFEAT * 2 + rowSlack);
  float* p = (float*)w;            w += aln((size_t)(N + 32) * 8);
  float2* q = (float2*)w;          w += aln((size_t)N * 8);
  unsigned short* W1p = (unsigned short*)w; w += aln((size_t)NFEAT * NHID * 2);
  unsigned short* W2p = (unsigned short*)w; w += aln((size_t)NHID * NFEAT * 2);

  // ---- CSR build: deterministic 2-pass partition (+ W pack on spare blocks)
  k_hist_pack<<<NBLK + 8, 1024, 0, stream>>>(colp, hist2d, E, nb, W1, W2, W1p,
                                             W2p);
  k_bsum<<<nS + 1, 256, 0, stream>>>(hist2d, psum, S, b2, Wl, bl, Cbuf);
  k_s3m<<<nS, 256, 0, stream>>>(hist2d, psum, sbase, S);
  k_part2<<<NBLK, 1024, 0, stream>>>(rowp, colp, sbase, tmp, E, nb);
  // bsort + per-bucket cvt: ebuf/offs/dinv + xs = bf16(dinv * X)
  k_bsort_cvt<<<nb, 256, 0, stream>>>(tmp, sbase, ebuf, offs, dinv, feat, xs,
                                      N, E, nb);
  // z = dinv .* (sum_in xs + xs_self)            [= A_norm @ X, bf16]
  k_agg_bf<<<(N + 3) / 4, 256, 0, stream>>>((const unsigned*)xs, offs, ebuf,
                                            dinv, (unsigned*)z, N);
  // p[i] = {(dinv_i*(relu(z@W1+b1)@W2)_i) . Wl_lo, . Wl_hi}  (g2 not stored)
  k_mfma_fused<<<(nrt + 1) / 2, 256, 0, stream>>>(z, W1p, W2p, b1, dinv, Wl, p);
  // q[i] = dinv[i]*(p[i] + sum_in p[src])
  k_agg_s<<<(N + 255) / 256, 256, 0, stream>>>((const float2*)p, offs, ebuf,
                                               dinv, q, N);
  // head: out = sigmoid(q1[m0] + q2[m1] + C)
  k_head2<<<(P + 255) / 256, 256, 0, stream>>>(q, mask, Cbuf, out, P);
}